// Round 7
// baseline (73.132 us; speedup 1.0000x reference)
//
#include <hip/hip_runtime.h>
#include <hip/hip_bf16.h>

typedef __attribute__((ext_vector_type(8))) short bf16x8;
typedef __attribute__((ext_vector_type(4))) float f32x4;
typedef __attribute__((ext_vector_type(4))) unsigned short u16x4;

#define MFMA16(a, b, c) __builtin_amdgcn_mfma_f32_16x16x32_bf16(a, b, c, 0, 0, 0)

// B=16, S=2048, EMB=512, HEAD_DIM=64
// Q pre-scaled by 0.125 * log2(e): softmax runs in exp2 domain.
#define QSCALE 0.18033688011112042f

#define GLDS16(gp, lp)                                                         \
    __builtin_amdgcn_global_load_lds(                                          \
        (const __attribute__((address_space(1))) void*)(gp),                   \
        (__attribute__((address_space(3))) void*)(lp), 16, 0, 0)

__device__ __forceinline__ short nbf(float f) {
    __hip_bfloat16 h = __float2bfloat16(f);
    return *(short*)&h;
}
__device__ __forceinline__ unsigned short nbfu(float f) {
    __hip_bfloat16 h = __float2bfloat16(f);
    return *(unsigned short*)&h;
}

// Wt[mat][h][e] = bf16(W_mat[e][h])
__global__ void wt_kernel(const float* __restrict__ Wq, const float* __restrict__ Wk,
                          const float* __restrict__ Wv, unsigned short* __restrict__ Wt) {
    const int h = blockIdx.x;
    const int mat = blockIdx.y;
    const int e = threadIdx.x;
    const float* W = (mat == 0) ? Wq : ((mat == 1) ? Wk : Wv);
    Wt[(mat * 64 + h) * 512 + e] = nbfu(W[e * 64 + h]);
}

// Fused QKV projection (unchanged from R5).
__global__ __launch_bounds__(256, 2) void qkv_proj(
    const float* __restrict__ x1, const unsigned short* __restrict__ Wt,
    unsigned short* __restrict__ Q, unsigned short* __restrict__ K,
    unsigned short* __restrict__ Vt)
{
    __shared__ char alds[2][8192];
    __shared__ char blds[2][12288];

    const int tid = threadIdx.x;
    const int w = tid >> 6, lane = tid & 63;
    const int c = lane & 15, g = lane >> 4;
    const int tokB = blockIdx.x * 64;

    const char* x1b = (const char*)x1;
    const char* Wtb = (const char*)Wt;

    const int tA0 = tid >> 3,           qA0 = (tid & 7) ^ (tA0 & 7);
    const int tA1 = (tid + 256) >> 3,   qA1 = (tid & 7) ^ (tA1 & 7);
    const size_t aoff0 = (size_t)(tokB + tA0) * 2048 + qA0 * 16;
    const size_t aoff1 = (size_t)(tokB + tA1) * 2048 + qA1 * 16;

    auto bsrc = [&](int j) -> size_t {
        const int n = j >> 6, c2 = (j >> 2) & 15, g2 = j & 3;
        return (size_t)((n >> 2) * 64 + (n & 3) * 16 + c2) * 1024 + g2 * 16;
    };
    const size_t boff0 = bsrc(tid), boff1 = bsrc(tid + 256), boff2 = bsrc(tid + 512);

    f32x4 acc[12];
#pragma unroll
    for (int n = 0; n < 12; ++n) acc[n] = (f32x4)0.f;

    GLDS16(x1b + aoff0, &alds[0][tid * 16]);
    GLDS16(x1b + aoff1, &alds[0][4096 + tid * 16]);
    GLDS16(Wtb + boff0, &blds[0][tid * 16]);
    GLDS16(Wtb + boff1, &blds[0][4096 + tid * 16]);
    GLDS16(Wtb + boff2, &blds[0][8192 + tid * 16]);

    const int arow = (w * 16 + c) * 128;
    const int aq0 = (((2 * g) ^ (c & 7)) * 16);
    const int aq1 = (((2 * g + 1) ^ (c & 7)) * 16);
    const int brd = (c * 4 + g) * 16;

    int buf = 0;
    for (int ks = 0; ks < 16; ++ks) {
        asm volatile("s_waitcnt vmcnt(0)\n\ts_barrier" ::: "memory");

        if (ks < 15) {
            const size_t ka = (size_t)(ks + 1) * 128;
            const size_t kb = (size_t)(ks + 1) * 64;
            char* ab = &alds[buf ^ 1][0];
            char* bb = &blds[buf ^ 1][0];
            GLDS16(x1b + aoff0 + ka, ab + tid * 16);
            GLDS16(x1b + aoff1 + ka, ab + 4096 + tid * 16);
            GLDS16(Wtb + boff0 + kb, bb + tid * 16);
            GLDS16(Wtb + boff1 + kb, bb + 4096 + tid * 16);
            GLDS16(Wtb + boff2 + kb, bb + 8192 + tid * 16);
        }

        const char* ab = &alds[buf][0];
        const char* bb = &blds[buf][0];
        f32x4 a0 = *(const f32x4*)(ab + arow + aq0);
        f32x4 a1 = *(const f32x4*)(ab + arow + aq1);
        bf16x8 af;
        af[0] = nbf(a0[0]); af[1] = nbf(a0[1]); af[2] = nbf(a0[2]); af[3] = nbf(a0[3]);
        af[4] = nbf(a1[0]); af[5] = nbf(a1[1]); af[6] = nbf(a1[2]); af[7] = nbf(a1[3]);
#pragma unroll
        for (int n = 0; n < 12; ++n) {
            bf16x8 bf = *(const bf16x8*)(bb + n * 1024 + brd);
            acc[n] = MFMA16(af, bf, acc[n]);
        }
        buf ^= 1;
    }

    const int tok0 = tokB + w * 16;
#pragma unroll
    for (int n = 0; n < 4; ++n)
#pragma unroll
        for (int r = 0; r < 4; ++r)
            Q[(size_t)(tok0 + g * 4 + r) * 64 + n * 16 + c] = nbfu(acc[n][r] * QSCALE);
#pragma unroll
    for (int n = 0; n < 4; ++n)
#pragma unroll
        for (int r = 0; r < 4; ++r)
            K[(size_t)(tok0 + g * 4 + r) * 64 + n * 16 + c] = nbfu(acc[4 + n][r]);

    const int b = tok0 >> 11;
    const int sl = (tok0 & 2047) + g * 4;
#pragma unroll
    for (int n = 0; n < 4; ++n) {
        const int d = n * 16 + c;
        u16x4 pv;
#pragma unroll
        for (int r = 0; r < 4; ++r) pv[r] = nbfu(acc[8 + n][r]);
        *(u16x4*)(Vt + ((size_t)(b * 64 + d) << 11) + sl) = pv;
    }
}

// Causal flash attention v5b (v5 with the K-tile advance constant fixed:
// 128 key rows x 128 B/row = 16384 bytes per tile, NOT 32768).
__global__ __launch_bounds__(256, 2) void flash_attn(
    const unsigned short* __restrict__ Q, const unsigned short* __restrict__ K,
    const unsigned short* __restrict__ Vt, float* __restrict__ out)
{
    __shared__ char kv[2][32768];   // [buf][ K:0..16383 | V:16384..32767 ]
    __shared__ char p_lds[16384];   // [wave][ps=4][lane=64]x16B

    const int tid = threadIdx.x;
    const int w = tid >> 6;
    const int lane = tid & 63;
    const int c = lane & 15, g = lane >> 4;

    const int id = blockIdx.x;
    const int xcd = id & 7;
    const int b = 2 * xcd + ((id >> 3) & 1);    // per-XCD batch pair -> L2-resident K/V
    const int bxx = id >> 4;
    const int qt = (bxx < 16) ? bxx : 47 - bxx; // CU pair (id,id+256): qt sum = 31
    const int qr0c = qt * 64 + w * 16 + c;      // this lane's q row (within batch)
    const size_t qrow_g = ((size_t)b << 11) + qt * 64 + w * 16;

    bf16x8 qf0 = *(const bf16x8*)(Q + (qrow_g + c) * 64 + g * 8);
    bf16x8 qf1 = *(const bf16x8*)(Q + (qrow_g + c) * 64 + 32 + g * 8);

    const char* Kb = (const char*)(K + (((size_t)b << 11) * 64));
    const char* Vb = (const char*)(Vt + (((size_t)b << 11) * 64));   // [d=64][s=2048]

    // staging: wave w stages n-block nn=w; per thread 4 K + 4 V chunks (h,s).
    const int nn = w;
    const int g2 = (tid >> 4) & 3, c2 = tid & 15;
    const size_t ksrc0 = (size_t)(nn * 16 + c2) * 128 + g2 * 16;   // + h*8192 + s*64
    const size_t vsrc0 = (size_t)(nn * 16 + c2) * 4096 + g2 * 16;  // + h*128  + s*64
    const int kdst0 = nn * 1024 + lane * 16;                       // + h*8192 + s*4096
    const int vdst0 = 16384 + kdst0;

    float m_run = -1e30f, l_run = 0.f;
    f32x4 acc_o[4];
#pragma unroll
    for (int n = 0; n < 4; ++n) acc_o[n] = (f32x4)0.f;

    const int n_iter = (qt >> 1) + 1;

    int buf = 0;
    {   // prologue: stage tile 0 into buf 0 (8 GLDS)
        char* d = &kv[0][0];
#pragma unroll
        for (int h = 0; h < 2; ++h)
#pragma unroll
            for (int s = 0; s < 2; ++s) {
                GLDS16(Kb + ksrc0 + h * 8192 + s * 64, d + kdst0 + h * 8192 + s * 4096);
                GLDS16(Vb + vsrc0 + h * 128 + s * 64,  d + vdst0 + h * 8192 + s * 4096);
            }
    }

    for (int kt2 = 0; kt2 < n_iter; ++kt2) {
        asm volatile("s_waitcnt vmcnt(0)\n\ts_barrier" ::: "memory");

        if (kt2 + 1 < n_iter) {
            const size_t ko = (size_t)(kt2 + 1) * 16384;  // 128 key rows x 128 B
            const size_t vo = (size_t)(kt2 + 1) * 256;    // 128 seq elems x 2 B
            char* d = &kv[buf ^ 1][0];
#pragma unroll
            for (int h = 0; h < 2; ++h)
#pragma unroll
                for (int s = 0; s < 2; ++s) {
                    GLDS16(Kb + ko + ksrc0 + h * 8192 + s * 64, d + kdst0 + h * 8192 + s * 4096);
                    GLDS16(Vb + vo + vsrc0 + h * 128 + s * 64,  d + vdst0 + h * 8192 + s * 4096);
                }
        }

        // ---- S^T = K Q^T for both halves (16 ds_read_b128, 16 MFMA) ----
        const char* kb = &kv[buf][0];
        f32x4 s[8];
#pragma unroll
        for (int i = 0; i < 8; ++i) s[i] = (f32x4)0.f;
        __builtin_amdgcn_s_setprio(1);
#pragma unroll
        for (int h = 0; h < 2; ++h)
#pragma unroll
            for (int n = 0; n < 4; ++n) {
                bf16x8 ka0 = *(const bf16x8*)(kb + h * 8192 + n * 1024 + lane * 16);
                bf16x8 ka1 = *(const bf16x8*)(kb + h * 8192 + 4096 + n * 1024 + lane * 16);
                s[h * 4 + n] = MFMA16(ka0, qf0, s[h * 4 + n]);
                s[h * 4 + n] = MFMA16(ka1, qf1, s[h * 4 + n]);
            }
        __builtin_amdgcn_s_setprio(0);

        // ---- causal mask (last iteration only) ----
        if (kt2 == (qt >> 1)) {
#pragma unroll
            for (int h = 0; h < 2; ++h)
#pragma unroll
                for (int n = 0; n < 4; ++n) {
                    const int key0 = kt2 * 128 + h * 64 + n * 16 + g * 4;
#pragma unroll
                    for (int r = 0; r < 4; ++r)
                        if (key0 + r > qr0c) s[h * 4 + n][r] = -1e30f;
                }
        }

        // ---- online softmax over 128 keys (exp2 domain, defer-max) ----
        float tm = -1e30f;
#pragma unroll
        for (int i = 0; i < 8; ++i)
            tm = fmaxf(tm, fmaxf(fmaxf(s[i][0], s[i][1]), fmaxf(s[i][2], s[i][3])));
        tm = fmaxf(tm, __shfl_xor(tm, 16, 64));
        tm = fmaxf(tm, __shfl_xor(tm, 32, 64));

        if (__any(tm > m_run + 8.f)) {
            const float mn = fmaxf(m_run, tm);
            const float alpha = exp2f(m_run - mn);
            m_run = mn;
            l_run *= alpha;
            float al[4];
#pragma unroll
            for (int r = 0; r < 4; ++r) al[r] = __shfl(alpha, g * 4 + r, 16);
#pragma unroll
            for (int n = 0; n < 4; ++n)
#pragma unroll
                for (int r = 0; r < 4; ++r) acc_o[n][r] *= al[r];
        }

        // P fragment write: dest = w*4096 + ps*1024 + gp*256 + c*16 + (g&1)*8 + 2r
        // ps = h*2+(n>>1), gp = (n&1)*2+(g>>1); 2-way bank aliasing only.
        char* pw = &p_lds[w * 4096 + ((g >> 1) * 16 + c) * 16 + (g & 1) * 8];
        float rs = 0.f;
#pragma unroll
        for (int h = 0; h < 2; ++h)
#pragma unroll
            for (int n = 0; n < 4; ++n) {
                const int i = h * 4 + n;
                float p0 = exp2f(s[i][0] - m_run);
                float p1 = exp2f(s[i][1] - m_run);
                float p2 = exp2f(s[i][2] - m_run);
                float p3 = exp2f(s[i][3] - m_run);
                rs += (p0 + p1) + (p2 + p3);
                u16x4 pk;
                pk[0] = nbfu(p0); pk[1] = nbfu(p1); pk[2] = nbfu(p2); pk[3] = nbfu(p3);
                *(u16x4*)(pw + (h * 2 + (n >> 1)) * 1024 + (n & 1) * 512) = pk;
            }
        rs += __shfl_xor(rs, 16, 64);
        rs += __shfl_xor(rs, 32, 64);
        l_run += rs;

        // ---- O += P V (4 P reads, 16 V reads, 16 MFMA; all conflict-free) ----
        const char* pr = &p_lds[w * 4096 + lane * 16];
        bf16x8 pf[4];
#pragma unroll
        for (int ps = 0; ps < 4; ++ps) pf[ps] = *(const bf16x8*)(pr + ps * 1024);
        const char* vb = &kv[buf][16384];
        __builtin_amdgcn_s_setprio(1);
#pragma unroll
        for (int n = 0; n < 4; ++n) {
#pragma unroll
            for (int ps = 0; ps < 4; ++ps) {
                bf16x8 vf = *(const bf16x8*)(vb + (ps >> 1) * 8192 + (ps & 1) * 4096 + n * 1024 + lane * 16);
                acc_o[n] = MFMA16(pf[ps], vf, acc_o[n]);
            }
        }
        __builtin_amdgcn_s_setprio(0);

        buf ^= 1;
    }

    const float inv_l = 1.f / l_run;
    float il[4];
#pragma unroll
    for (int r = 0; r < 4; ++r) il[r] = __shfl(inv_l, g * 4 + r, 16);
#pragma unroll
    for (int n = 0; n < 4; ++n)
#pragma unroll
        for (int r = 0; r < 4; ++r)
            out[(qrow_g + g * 4 + r) * 64 + n * 16 + c] = acc_o[n][r] * il[r];
}

extern "C" void kernel_launch(void* const* d_in, const int* in_sizes, int n_in,
                              void* d_out, int out_size, void* d_ws, size_t ws_size,
                              hipStream_t stream) {
    const float* x1 = (const float*)d_in[0];
    const float* Wq = (const float*)d_in[2];
    const float* Wk = (const float*)d_in[3];
    const float* Wv = (const float*)d_in[4];
    float* out = (float*)d_out;

    unsigned short* Wt  = (unsigned short*)d_ws;
    unsigned short* Qw  = (unsigned short*)((char*)d_ws + 196608);
    unsigned short* Kw  = (unsigned short*)((char*)d_ws + 196608 + 4194304);
    unsigned short* Vtw = (unsigned short*)((char*)d_ws + 196608 + 2 * 4194304);

    wt_kernel<<<dim3(64, 3), 512, 0, stream>>>(Wq, Wk, Wv, Wt);
    qkv_proj<<<512, 256, 0, stream>>>(x1, Wt, Qw, Kw, Vtw);
    flash_attn<<<512, 256, 0, stream>>>(Qw, Kw, Vtw, out);
}